// Round 5
// baseline (573.639 us; speedup 1.0000x reference)
//
#include <hip/hip_runtime.h>
#include <hip/hip_bf16.h>

#define H_DIM 1024
#define I_DIM 2048
#define NE 8
#define NT 4096

typedef __bf16 bf16x8 __attribute__((ext_vector_type(8)));
typedef __bf16 bf16x4 __attribute__((ext_vector_type(4)));
typedef float f32x4 __attribute__((ext_vector_type(4)));

// 16B-chunk index within a [rows][8-chunk] LDS tile, XOR-swizzled so lanes
// reading different rows at the same k-chunk hit different bank groups.
__device__ __forceinline__ int swzc(int r, int j) { return r * 8 + (j ^ (r & 7)); }

// async global->LDS, 16B per lane. LDS dest is wave-uniform base (HW adds lane*16).
__device__ __forceinline__ void gl16(const void* g, void* l) {
  __builtin_amdgcn_global_load_lds(
      (const __attribute__((address_space(1))) unsigned int*)g,
      (__attribute__((address_space(3))) unsigned int*)l, 16, 0, 0);
}

__device__ __forceinline__ bf16x8 cvt8(float4 a, float4 b) {
  bf16x8 r;
  r[0] = (__bf16)a.x; r[1] = (__bf16)a.y; r[2] = (__bf16)a.z; r[3] = (__bf16)a.w;
  r[4] = (__bf16)b.x; r[5] = (__bf16)b.y; r[6] = (__bf16)b.z; r[7] = (__bf16)b.w;
  return r;
}

// One-shot cast of all six weight matrices fp32->bf16 (pow2 region sizes).
__global__ __launch_bounds__(256) void k_castall(
    const float* __restrict__ wg, const float* __restrict__ wu,
    const float* __restrict__ wd, const float* __restrict__ sg,
    const float* __restrict__ su, const float* __restrict__ sd,
    __bf16* __restrict__ wgb, __bf16* __restrict__ wub, __bf16* __restrict__ wdb,
    __bf16* __restrict__ sgb, __bf16* __restrict__ sub, __bf16* __restrict__ sdb) {
  long long i = (long long)blockIdx.x * 256 + threadIdx.x;
  const long long NW = 1LL << 21, NS = 1LL << 18;
  const float* s; __bf16* d; int off;
  if (i < 3 * NW) {
    int r = (int)(i >> 21); off = (int)(i & (NW - 1));
    s = (r == 0) ? wg : (r == 1) ? wu : wd;
    d = (r == 0) ? wgb : (r == 1) ? wub : wdb;
  } else {
    long long j = i - 3 * NW;
    int r = (int)(j >> 18); off = (int)(j & (NS - 1));
    s = (r == 0) ? sg : (r == 1) ? su : sd;
    d = (r == 0) ? sgb : (r == 1) ? sub : sdb;
  }
  const float4* s4 = (const float4*)s;
  float4 a = s4[(size_t)off * 2], b = s4[(size_t)off * 2 + 1];
  ((bf16x8*)d)[off] = cvt8(a, b);
}

// Router: sigmoid top-2 renorm + per-expert token lists; fuses x -> bf16 cast.
__global__ __launch_bounds__(256) void k_router(const float* __restrict__ x,
                                                const float* __restrict__ rw,
                                                const float* __restrict__ rbias,
                                                __bf16* __restrict__ xb,
                                                int* __restrict__ counts,
                                                int* __restrict__ list,
                                                int* __restrict__ tE,
                                                int* __restrict__ tP,
                                                float* __restrict__ tG) {
  int wv = threadIdx.x >> 6, lane = threadIdx.x & 63;
  int t = blockIdx.x * 4 + wv;
  float acc[NE];
#pragma unroll
  for (int e = 0; e < NE; e++) acc[e] = 0.f;
  const float4* xr = (const float4*)(x + (size_t)t * H_DIM);
  const float4* wr4 = (const float4*)rw;
  bf16x4* xo = (bf16x4*)xb + (size_t)t * (H_DIM / 4);
#pragma unroll
  for (int it = 0; it < 4; ++it) {
    int c = it * 64 + lane;
    float4 xv = xr[c];
    bf16x4 bv;
    bv[0] = (__bf16)xv.x; bv[1] = (__bf16)xv.y;
    bv[2] = (__bf16)xv.z; bv[3] = (__bf16)xv.w;
    xo[c] = bv;
#pragma unroll
    for (int e = 0; e < NE; e++) {
      float4 wv = wr4[e * (H_DIM / 4) + c];
      acc[e] += xv.x * wv.x + xv.y * wv.y + xv.z * wv.z + xv.w * wv.w;
    }
  }
#pragma unroll
  for (int e = 0; e < NE; e++) {
#pragma unroll
    for (int off = 32; off > 0; off >>= 1) acc[e] += __shfl_xor(acc[e], off, 64);
  }
  if (lane == 0) {
    float p[NE];
#pragma unroll
    for (int e = 0; e < NE; e++) p[e] = 1.f / (1.f + expf(-(acc[e] + rbias[e])));
    int e0 = 0;
#pragma unroll
    for (int e = 1; e < NE; e++) if (p[e] > p[e0]) e0 = e;
    int e1 = -1;
#pragma unroll
    for (int e = 0; e < NE; e++) if (e != e0 && (e1 < 0 || p[e] > p[e1])) e1 = e;
    float s = p[e0] + p[e1];
    float g0 = p[e0] / s, g1 = p[e1] / s;
    int p0 = atomicAdd(&counts[e0], 1);
    int p1 = atomicAdd(&counts[e1], 1);
    list[e0 * NT + p0] = t;
    list[e1 * NT + p1] = t;
    tE[t * 2] = e0; tE[t * 2 + 1] = e1;
    tP[t * 2] = p0; tP[t * 2 + 1] = p1;
    tG[t * 2] = g0; tG[t * 2 + 1] = g1;
  }
}

__global__ void k_prefix(const int* __restrict__ counts, int* __restrict__ bases) {
  if (threadIdx.x == 0) {
    int s = 0;
    for (int e = 0; e < NE; e++) { bases[e] = s; s += counts[e]; }
  }
}

// ---------------------------------------------------------------------------
// Fused gate+up GEMM. Tile: 256 token-rows x (128 g-cols + 128 u-cols).
// B-tile rows interleave g/u per 64-row quarter: rows q*64+[0,32) = g cols
// n0+q*32+[0,32); rows q*64+[32,64) = u cols (same) -> each wave owns matching
// g/u columns, silu pairing stays wave-local.
// Pipeline: per K-tile (BK=64): vmcnt(0)+barrier at top (drains loads issued
// one full tile earlier), immediately issue all 8 gl16 for kt+1 into the
// other buffer, then free-running ds_read+MFMA (no mid-tile syncs).
// ---------------------------------------------------------------------------
__global__ __launch_bounds__(512, 2) void k_upgate8(
    const __bf16* __restrict__ xb, const __bf16* __restrict__ wgb,
    const __bf16* __restrict__ wub, const __bf16* __restrict__ sgb,
    const __bf16* __restrict__ sub, const int* __restrict__ counts,
    const int* __restrict__ bases, const int* __restrict__ list,
    __bf16* __restrict__ hs, __bf16* __restrict__ hr) {
  const int NWG = (I_DIM / 128) * (NT / 256) * (NE + 1);  // 2304
  int orig = blockIdx.x;
  int wgid = (orig & 7) * (NWG >> 3) + (orig >> 3);       // bijective XCD chunk
  int z = wgid >> 8;                                      // 256 wgs per z
  int rem = wgid & 255;
  int xbk = rem >> 4, ybk = rem & 15;                     // y innermost: same-XCD
  int m0 = ybk * 256, n0 = xbk * 128;                     // neighbors share B panel
  bool sh = (z == NE);
  int count, base;
  const __bf16 *Bg, *Bu;
  if (sh) {
    count = NT; base = 0; Bg = sgb; Bu = sub;
  } else {
    count = counts[z];
    if (m0 >= count) return;
    base = bases[z];
    Bg = wgb + (size_t)z * (I_DIM * H_DIM);
    Bu = wub + (size_t)z * (I_DIM * H_DIM);
  }

  __shared__ bf16x8 lds[8192];   // [buf][A 2048 | B 2048] -> 128 KB

  int tid = threadIdx.x, lane = tid & 63, w = tid >> 6;
  int wm = w >> 2, wn = w & 3;
  int fr = lane & 15, fs = lane >> 4;

  const bf16x8* a8 = (const bf16x8*)xb;
  const bf16x8* g8 = (const bf16x8*)Bg;
  const bf16x8* u8 = (const bf16x8*)Bu;

  // per-thread staged-chunk sources (pre-swizzled so linear LDS dest content
  // matches the swizzled read pattern)
  const bf16x8* pA[4];
  const bf16x8* pB[4];
#pragma unroll
  for (int q = 0; q < 4; q++) {
    int c = q * 512 + tid;
    int r = c >> 3, j = (c & 7) ^ (r & 7);
    int gr = m0 + r;
    int tok = sh ? gr : ((gr < count) ? list[z * NT + gr] : list[z * NT]);
    pA[q] = a8 + tok * (H_DIM / 8) + j;
    int q2 = r >> 6, rr = r & 63;
    if (rr < 32) pB[q] = g8 + (size_t)(n0 + q2 * 32 + rr) * (H_DIM / 8) + j;
    else         pB[q] = u8 + (size_t)(n0 + q2 * 32 + (rr - 32)) * (H_DIM / 8) + j;
  }

  f32x4 accg[8][2], accu[8][2];
#pragma unroll
  for (int m = 0; m < 8; m++)
#pragma unroll
    for (int n = 0; n < 2; n++) {
      accg[m][n] = (f32x4){0.f, 0.f, 0.f, 0.f};
      accu[m][n] = (f32x4){0.f, 0.f, 0.f, 0.f};
    }

  const int NK = H_DIM / 64;  // 16 K-tiles
  // prologue: stage tile 0 into buf 0
  {
    bf16x8* dA = lds;
    bf16x8* dB = lds + 2048;
#pragma unroll
    for (int q = 0; q < 4; q++) gl16(pA[q], dA + q * 512 + w * 64);
#pragma unroll
    for (int q = 0; q < 4; q++) gl16(pB[q], dB + q * 512 + w * 64);
  }

  for (int kt = 0; kt < NK; ++kt) {
    asm volatile("s_waitcnt vmcnt(0)" ::: "memory");  // tile kt landed (aged 1 tile)
    __builtin_amdgcn_s_barrier();                     // publish + WAR fence
    asm volatile("" ::: "memory");
    if (kt + 1 < NK) {                                // issue-early: tile kt+1
      bf16x8* dA = lds + ((kt + 1) & 1) * 4096;
      bf16x8* dB = dA + 2048;
      int ko = (kt + 1) * 8;
#pragma unroll
      for (int q = 0; q < 4; q++) gl16(pA[q] + ko, dA + q * 512 + w * 64);
#pragma unroll
      for (int q = 0; q < 4; q++) gl16(pB[q] + ko, dB + q * 512 + w * 64);
    }
    const bf16x8* A = lds + (kt & 1) * 4096;
    const bf16x8* B = A + 2048;
#pragma unroll
    for (int ks = 0; ks < 2; ks++) {
      bf16x8 af[8], bfr[4];
#pragma unroll
      for (int mf = 0; mf < 8; mf++) af[mf] = A[swzc(wm * 128 + mf * 16 + fr, ks * 4 + fs)];
#pragma unroll
      for (int nf = 0; nf < 4; nf++) bfr[nf] = B[swzc(wn * 64 + nf * 16 + fr, ks * 4 + fs)];
      __builtin_amdgcn_s_setprio(1);
#pragma unroll
      for (int m = 0; m < 8; m++)
#pragma unroll
        for (int n = 0; n < 2; n++) {
          accg[m][n] = __builtin_amdgcn_mfma_f32_16x16x32_bf16(af[m], bfr[n], accg[m][n], 0, 0, 0);
          accu[m][n] = __builtin_amdgcn_mfma_f32_16x16x32_bf16(af[m], bfr[n + 2], accu[m][n], 0, 0, 0);
        }
      __builtin_amdgcn_s_setprio(0);
    }
  }

#pragma unroll
  for (int m = 0; m < 8; m++)
#pragma unroll
    for (int n = 0; n < 2; n++)
#pragma unroll
      for (int q2 = 0; q2 < 4; q2++) {
        int row = wm * 128 + m * 16 + fs * 4 + q2;
        int col = n0 + wn * 32 + n * 16 + fr;
        float g = accg[m][n][q2], u = accu[m][n][q2];
        float h = g * u / (1.f + expf(-g));  // silu(g)*u
        __bf16 hb = (__bf16)h;
        int grow = m0 + row;
        if (sh) hs[(size_t)grow * I_DIM + col] = hb;
        else if (grow < count) hr[(size_t)(base + grow) * I_DIM + col] = hb;
      }
}

// Down GEMM. Tile 256x256, same free-running K-tile pipeline.
__global__ __launch_bounds__(512, 2) void k_down8(
    const __bf16* __restrict__ hs, const __bf16* __restrict__ hr,
    const __bf16* __restrict__ wdb, const __bf16* __restrict__ sdb,
    const int* __restrict__ counts, const int* __restrict__ bases,
    float* __restrict__ out, float* __restrict__ y) {
  const int NWG = (H_DIM / 256) * (NT / 256) * (NE + 1);  // 576
  int orig = blockIdx.x;
  int wgid = (orig & 7) * (NWG >> 3) + (orig >> 3);
  int z = wgid >> 6;                                      // 64 wgs per z
  int rem = wgid & 63;
  int xbk = rem >> 4, ybk = rem & 15;
  int m0 = ybk * 256, n0 = xbk * 256;
  bool sh = (z == NE);
  int count, base;
  const __bf16 *B, *A;
  if (sh) {
    count = NT; base = 0; B = sdb; A = hs;
  } else {
    count = counts[z];
    if (m0 >= count) return;
    base = bases[z];
    B = wdb + (size_t)z * (H_DIM * I_DIM);
    A = hr + (size_t)base * I_DIM;
  }

  __shared__ bf16x8 lds[8192];   // 128 KB

  int tid = threadIdx.x, lane = tid & 63, w = tid >> 6;
  int wm = w >> 2, wn = w & 3;
  int fr = lane & 15, fs = lane >> 4;

  const bf16x8* a8 = (const bf16x8*)A;
  const bf16x8* b8 = (const bf16x8*)B;

  const bf16x8* pA[4];
  const bf16x8* pB[4];
#pragma unroll
  for (int q = 0; q < 4; q++) {
    int c = q * 512 + tid;
    int r = c >> 3, j = (c & 7) ^ (r & 7);
    int ra = m0 + r; if (ra >= count) ra = count - 1;
    pA[q] = a8 + (size_t)ra * (I_DIM / 8) + j;
    pB[q] = b8 + (size_t)(n0 + r) * (I_DIM / 8) + j;
  }

  f32x4 acc[8][4];
#pragma unroll
  for (int m = 0; m < 8; m++)
#pragma unroll
    for (int n = 0; n < 4; n++) acc[m][n] = (f32x4){0.f, 0.f, 0.f, 0.f};

  const int NK = I_DIM / 64;  // 32 K-tiles
  {
    bf16x8* dA = lds;
    bf16x8* dB = lds + 2048;
#pragma unroll
    for (int q = 0; q < 4; q++) gl16(pA[q], dA + q * 512 + w * 64);
#pragma unroll
    for (int q = 0; q < 4; q++) gl16(pB[q], dB + q * 512 + w * 64);
  }

  for (int kt = 0; kt < NK; ++kt) {
    asm volatile("s_waitcnt vmcnt(0)" ::: "memory");
    __builtin_amdgcn_s_barrier();
    asm volatile("" ::: "memory");
    if (kt + 1 < NK) {
      bf16x8* dA = lds + ((kt + 1) & 1) * 4096;
      bf16x8* dB = dA + 2048;
      int ko = (kt + 1) * 8;
#pragma unroll
      for (int q = 0; q < 4; q++) gl16(pA[q] + ko, dA + q * 512 + w * 64);
#pragma unroll
      for (int q = 0; q < 4; q++) gl16(pB[q] + ko, dB + q * 512 + w * 64);
    }
    const bf16x8* Ac = lds + (kt & 1) * 4096;
    const bf16x8* Bc = Ac + 2048;
#pragma unroll
    for (int ks = 0; ks < 2; ks++) {
      bf16x8 af[8], bfr[4];
#pragma unroll
      for (int mf = 0; mf < 8; mf++) af[mf] = Ac[swzc(wm * 128 + mf * 16 + fr, ks * 4 + fs)];
#pragma unroll
      for (int nf = 0; nf < 4; nf++) bfr[nf] = Bc[swzc(wn * 64 + nf * 16 + fr, ks * 4 + fs)];
      __builtin_amdgcn_s_setprio(1);
#pragma unroll
      for (int m = 0; m < 8; m++)
#pragma unroll
        for (int n = 0; n < 4; n++)
          acc[m][n] = __builtin_amdgcn_mfma_f32_16x16x32_bf16(af[m], bfr[n], acc[m][n], 0, 0, 0);
      __builtin_amdgcn_s_setprio(0);
    }
  }

#pragma unroll
  for (int m = 0; m < 8; m++)
#pragma unroll
    for (int n = 0; n < 4; n++)
#pragma unroll
      for (int q2 = 0; q2 < 4; q2++) {
        int row = wm * 128 + m * 16 + fs * 4 + q2;
        int col = n0 + wn * 64 + n * 16 + fr;
        float v = acc[m][n][q2];
        int grow = m0 + row;
        if (sh) out[(size_t)grow * H_DIM + col] = v;
        else if (grow < count) y[(size_t)(base + grow) * H_DIM + col] = v;
      }
}

__global__ __launch_bounds__(256) void k_combine(
    const float* __restrict__ y, const int* __restrict__ bases,
    const int* __restrict__ tE, const int* __restrict__ tP,
    const float* __restrict__ tG, float* __restrict__ out) {
  int t = blockIdx.x;
  int c = threadIdx.x;  // H/4 = 256 float4 per token row
  int e0 = tE[t * 2], e1 = tE[t * 2 + 1];
  int r0 = bases[e0] + tP[t * 2], r1 = bases[e1] + tP[t * 2 + 1];
  float g0 = tG[t * 2], g1 = tG[t * 2 + 1];
  const float4* y4 = (const float4*)y;
  float4* o4 = (float4*)out;
  float4 s = o4[(size_t)t * (H_DIM / 4) + c];
  float4 a = y4[(size_t)r0 * (H_DIM / 4) + c];
  float4 b = y4[(size_t)r1 * (H_DIM / 4) + c];
  s.x += g0 * a.x + g1 * b.x;
  s.y += g0 * a.y + g1 * b.y;
  s.z += g0 * a.z + g1 * b.z;
  s.w += g0 * a.w + g1 * b.w;
  o4[(size_t)t * (H_DIM / 4) + c] = s;
}

extern "C" void kernel_launch(void* const* d_in, const int* in_sizes, int n_in,
                              void* d_out, int out_size, void* d_ws, size_t ws_size,
                              hipStream_t stream) {
  const float* x = (const float*)d_in[0];
  const float* sg_w = (const float*)d_in[1];
  const float* su_w = (const float*)d_in[2];
  const float* sd_w = (const float*)d_in[3];
  const float* router_w = (const float*)d_in[4];
  const float* routing_bias = (const float*)d_in[5];
  const float* wg = (const float*)d_in[6];
  const float* wu = (const float*)d_in[7];
  const float* wd = (const float*)d_in[8];
  float* out = (float*)d_out;
  char* ws = (char*)d_ws;

  __bf16* xb  = (__bf16*)(ws + 0);            //  8,388,608
  __bf16* hs  = (__bf16*)(ws + 8388608);      // 16,777,216
  __bf16* hr  = (__bf16*)(ws + 25165824);     // 33,554,432
  float*  y   = (float*)(ws + 58720256);      // 33,554,432
  __bf16* wgb = (__bf16*)(ws + 92274688);     // 33,554,432
  __bf16* wub = (__bf16*)(ws + 125829120);    // 33,554,432
  __bf16* wdb = (__bf16*)(ws + 159383552);    // 33,554,432
  __bf16* sgb = (__bf16*)(ws + 192937984);    //  4,194,304
  __bf16* sub = (__bf16*)(ws + 197132288);    //  4,194,304
  __bf16* sdb = (__bf16*)(ws + 201326592);    //  4,194,304
  int* counts = (int*)(ws + 205520896);
  int* bases  = (int*)(ws + 205520928);
  int* list   = (int*)(ws + 205520960);       // 131,072
  int* tE     = (int*)(ws + 205652032);       // 32,768
  int* tP     = (int*)(ws + 205684800);       // 32,768
  float* tG   = (float*)(ws + 205717568);     // 32,768

  hipMemsetAsync(counts, 0, NE * sizeof(int), stream);
  k_castall<<<27648, 256, 0, stream>>>(wg, wu, wd, sg_w, su_w, sd_w,
                                       wgb, wub, wdb, sgb, sub, sdb);
  k_router<<<NT / 4, 256, 0, stream>>>(x, router_w, routing_bias, xb,
                                       counts, list, tE, tP, tG);
  k_prefix<<<1, 64, 0, stream>>>(counts, bases);
  k_upgate8<<<(I_DIM / 128) * (NT / 256) * (NE + 1), 512, 0, stream>>>(
      xb, wgb, wub, sgb, sub, counts, bases, list, hs, hr);
  k_down8<<<(H_DIM / 256) * (NT / 256) * (NE + 1), 512, 0, stream>>>(
      hs, hr, wdb, sdb, counts, bases, out, y);
  k_combine<<<NT, 256, 0, stream>>>(y, bases, tE, tP, tG, out);
}

// Round 6
// 428.773 us; speedup vs baseline: 1.3379x; 1.3379x over previous
//
#include <hip/hip_runtime.h>
#include <hip/hip_bf16.h>

#define H_DIM 1024
#define I_DIM 2048
#define NE 8
#define NT 4096

typedef __bf16 bf16x8 __attribute__((ext_vector_type(8)));
typedef __bf16 bf16x4 __attribute__((ext_vector_type(4)));
typedef float f32x4 __attribute__((ext_vector_type(4)));

#define MEMFENCE asm volatile("" ::: "memory")

// 16B-chunk index within a [rows][8-chunk] LDS tile, XOR-swizzled (verified
// conflict-free in R1-R5: SQ_LDS_BANK_CONFLICT == 0).
__device__ __forceinline__ int swzc(int r, int j) { return r * 8 + (j ^ (r & 7)); }

// async global->LDS, 16B per lane. LDS dest is wave-uniform base (HW adds lane*16).
__device__ __forceinline__ void gl16(const void* g, void* l) {
  __builtin_amdgcn_global_load_lds(
      (const __attribute__((address_space(1))) unsigned int*)g,
      (__attribute__((address_space(3))) unsigned int*)l, 16, 0, 0);
}

__device__ __forceinline__ bf16x8 cvt8(float4 a, float4 b) {
  bf16x8 r;
  r[0] = (__bf16)a.x; r[1] = (__bf16)a.y; r[2] = (__bf16)a.z; r[3] = (__bf16)a.w;
  r[4] = (__bf16)b.x; r[5] = (__bf16)b.y; r[6] = (__bf16)b.z; r[7] = (__bf16)b.w;
  return r;
}

// One-shot cast of all six weight matrices fp32->bf16 (pow2 region sizes).
__global__ __launch_bounds__(256) void k_castall(
    const float* __restrict__ wg, const float* __restrict__ wu,
    const float* __restrict__ wd, const float* __restrict__ sg,
    const float* __restrict__ su, const float* __restrict__ sd,
    __bf16* __restrict__ wgb, __bf16* __restrict__ wub, __bf16* __restrict__ wdb,
    __bf16* __restrict__ sgb, __bf16* __restrict__ sub, __bf16* __restrict__ sdb) {
  long long i = (long long)blockIdx.x * 256 + threadIdx.x;
  const long long NW = 1LL << 21, NS = 1LL << 18;
  const float* s; __bf16* d; int off;
  if (i < 3 * NW) {
    int r = (int)(i >> 21); off = (int)(i & (NW - 1));
    s = (r == 0) ? wg : (r == 1) ? wu : wd;
    d = (r == 0) ? wgb : (r == 1) ? wub : wdb;
  } else {
    long long j = i - 3 * NW;
    int r = (int)(j >> 18); off = (int)(j & (NS - 1));
    s = (r == 0) ? sg : (r == 1) ? su : sd;
    d = (r == 0) ? sgb : (r == 1) ? sub : sdb;
  }
  const float4* s4 = (const float4*)s;
  float4 a = s4[(size_t)off * 2], b = s4[(size_t)off * 2 + 1];
  ((bf16x8*)d)[off] = cvt8(a, b);
}

// Router: sigmoid top-2 renorm + per-expert token lists; fuses x -> bf16 cast.
__global__ __launch_bounds__(256) void k_router(const float* __restrict__ x,
                                                const float* __restrict__ rw,
                                                const float* __restrict__ rbias,
                                                __bf16* __restrict__ xb,
                                                int* __restrict__ counts,
                                                int* __restrict__ list,
                                                int* __restrict__ tE,
                                                int* __restrict__ tP,
                                                float* __restrict__ tG) {
  int wv = threadIdx.x >> 6, lane = threadIdx.x & 63;
  int t = blockIdx.x * 4 + wv;
  float acc[NE];
#pragma unroll
  for (int e = 0; e < NE; e++) acc[e] = 0.f;
  const float4* xr = (const float4*)(x + (size_t)t * H_DIM);
  const float4* wr4 = (const float4*)rw;
  bf16x4* xo = (bf16x4*)xb + (size_t)t * (H_DIM / 4);
#pragma unroll
  for (int it = 0; it < 4; ++it) {
    int c = it * 64 + lane;
    float4 xv = xr[c];
    bf16x4 bv;
    bv[0] = (__bf16)xv.x; bv[1] = (__bf16)xv.y;
    bv[2] = (__bf16)xv.z; bv[3] = (__bf16)xv.w;
    xo[c] = bv;
#pragma unroll
    for (int e = 0; e < NE; e++) {
      float4 wv = wr4[e * (H_DIM / 4) + c];
      acc[e] += xv.x * wv.x + xv.y * wv.y + xv.z * wv.z + xv.w * wv.w;
    }
  }
#pragma unroll
  for (int e = 0; e < NE; e++) {
#pragma unroll
    for (int off = 32; off > 0; off >>= 1) acc[e] += __shfl_xor(acc[e], off, 64);
  }
  if (lane == 0) {
    float p[NE];
#pragma unroll
    for (int e = 0; e < NE; e++) p[e] = 1.f / (1.f + expf(-(acc[e] + rbias[e])));
    int e0 = 0;
#pragma unroll
    for (int e = 1; e < NE; e++) if (p[e] > p[e0]) e0 = e;
    int e1 = -1;
#pragma unroll
    for (int e = 0; e < NE; e++) if (e != e0 && (e1 < 0 || p[e] > p[e1])) e1 = e;
    float s = p[e0] + p[e1];
    float g0 = p[e0] / s, g1 = p[e1] / s;
    int p0 = atomicAdd(&counts[e0], 1);
    int p1 = atomicAdd(&counts[e1], 1);
    list[e0 * NT + p0] = t;
    list[e1 * NT + p1] = t;
    tE[t * 2] = e0; tE[t * 2 + 1] = e1;
    tP[t * 2] = p0; tP[t * 2 + 1] = p1;
    tG[t * 2] = g0; tG[t * 2 + 1] = g1;
  }
}

// ---------------------------------------------------------------------------
// Quadrant-phase GEMM schedule (derived m201 form), 8 waves, 512 thr, BK=64,
// 128 KB LDS (2 dbuf x [A 256x64 | B 256x64] bf16).
// Per K-tile: 4 phases, phase k = C-quadrant (Rk=k>>1, Ck=k&1).
//  k0: read af(R0) 4 + bf0(C0) 8; stage A0'; bar; lgkm0; 16 MFMA; vmcnt(4); bar
//  k1: read bf1(C1) 8;            stage B0'; bar; lgkm0; 16 MFMA; vmcnt(4); bar
//  k2: read af(R1) 4;             stage B1'; bar; lgkm0; 16 MFMA;            bar
//  k3: (no reads)                 stage A1'; bar;        16 MFMA; vmcnt(4); bar
// Every vmcnt(4) retires half-tiles staged >=3 phases earlier (never young).
// dbuf^1 is fully consumed during tile t-1, so staging t+1 into it is WAR-safe.
// ---------------------------------------------------------------------------

#define READ_AF(SRC, RB)                                                     \
  _Pragma("unroll") for (int m2 = 0; m2 < 2; m2++)                           \
  _Pragma("unroll") for (int ks = 0; ks < 2; ks++)                           \
    af[m2][ks] = (SRC)[swzc((RB) + wr * 32 + m2 * 16 + fr, ks * 4 + fs)];

#define READ_BF(SRC, DST, CB)                                                \
  _Pragma("unroll") for (int n = 0; n < 4; n++)                              \
  _Pragma("unroll") for (int ks = 0; ks < 2; ks++)                           \
    DST[n][ks] = (SRC)[swzc((CB) + wc * 64 + n * 16 + fr, ks * 4 + fs)];

#define MFMA16(ACC, BF)                                                      \
  _Pragma("unroll") for (int m2 = 0; m2 < 2; m2++)                           \
  _Pragma("unroll") for (int n = 0; n < 4; n++)                              \
  _Pragma("unroll") for (int ks = 0; ks < 2; ks++)                           \
    ACC[m2][n] = __builtin_amdgcn_mfma_f32_16x16x32_bf16(                    \
        af[m2][ks], BF[n][ks], ACC[m2][n], 0, 0, 0);

// Fused gate+up GEMM. Block: 256 token-rows x 128 out-cols (g AND u via
// interleaved B rows: b = G*64 + gu*32 + c -> (gu?u:g) col n0+G*32+c).
__global__ __launch_bounds__(512, 2) void k_upgate8(
    const __bf16* __restrict__ xb, const __bf16* __restrict__ wgb,
    const __bf16* __restrict__ wub, const __bf16* __restrict__ sgb,
    const __bf16* __restrict__ sub, const int* __restrict__ counts,
    const int* __restrict__ list,
    __bf16* __restrict__ hs, __bf16* __restrict__ hr) {
  int z = blockIdx.z;
  int m0 = blockIdx.y * 256, n0 = blockIdx.x * 128;
  bool sh = (z == NE);
  int count, base = 0;
  const __bf16 *Bg, *Bu;
  if (sh) {
    count = NT; Bg = sgb; Bu = sub;
  } else {
    count = counts[z];
    if (m0 >= count) return;
    for (int e = 0; e < z; e++) base += counts[e];
    Bg = wgb + (size_t)z * (I_DIM * H_DIM);
    Bu = wub + (size_t)z * (I_DIM * H_DIM);
  }

  __shared__ bf16x8 lds[8192];   // [dbuf][A 2048 | B 2048]

  int tid = threadIdx.x, lane = tid & 63, w = tid >> 6;
  int wr = w >> 1, wc = w & 1;
  int fr = lane & 15, fs = lane >> 4;

  const bf16x8* a8 = (const bf16x8*)xb;
  const bf16x8* g8 = (const bf16x8*)Bg;
  const bf16x8* u8 = (const bf16x8*)Bu;

  // staging sources (pre-swizzled): q covers rows q*64..q*64+63 of the tile
  const bf16x8* pA[4];
  const bf16x8* pB[4];
#pragma unroll
  for (int q = 0; q < 4; q++) {
    int c = q * 512 + tid;
    int r = c >> 3, j = (c & 7) ^ (r & 7);
    int gr = m0 + r;
    int tok = sh ? gr : ((gr < count) ? list[z * NT + gr] : list[z * NT]);
    pA[q] = a8 + (size_t)tok * (H_DIM / 8) + j;
    int G = r >> 6, gu = (r >> 5) & 1, cc = r & 31;
    pB[q] = (gu ? u8 : g8) + (size_t)(n0 + G * 32 + cc) * (H_DIM / 8) + j;
  }

  f32x4 acc0[2][4], acc1[2][4], acc2[2][4], acc3[2][4];
#pragma unroll
  for (int m2 = 0; m2 < 2; m2++)
#pragma unroll
    for (int n = 0; n < 4; n++) {
      acc0[m2][n] = (f32x4){0.f, 0.f, 0.f, 0.f};
      acc1[m2][n] = (f32x4){0.f, 0.f, 0.f, 0.f};
      acc2[m2][n] = (f32x4){0.f, 0.f, 0.f, 0.f};
      acc3[m2][n] = (f32x4){0.f, 0.f, 0.f, 0.f};
    }

  // prologue: stage tile 0 into dbuf0, half order A0,B0,B1,A1
  {
    bf16x8* dA = lds;
    bf16x8* dB = lds + 2048;
    gl16(pA[0], dA + 0 * 512 + w * 64); gl16(pA[1], dA + 1 * 512 + w * 64);
    gl16(pB[0], dB + 0 * 512 + w * 64); gl16(pB[1], dB + 1 * 512 + w * 64);
    gl16(pB[2], dB + 2 * 512 + w * 64); gl16(pB[3], dB + 3 * 512 + w * 64);
    gl16(pA[2], dA + 2 * 512 + w * 64); gl16(pA[3], dA + 3 * 512 + w * 64);
  }
  asm volatile("s_waitcnt vmcnt(4)" ::: "memory");  // A0,B0 landed
  __builtin_amdgcn_s_barrier();
  MEMFENCE;

  const int NK = H_DIM / 64;  // 16
  bf16x8 af[2][2], bf0[4][2], bf1[4][2];
  for (int kt = 0; kt < NK; ++kt) {
    const bf16x8* A = lds + (kt & 1) * 4096;
    const bf16x8* B = A + 2048;
    bf16x8* nA = lds + (((kt & 1) ^ 1)) * 4096;
    bf16x8* nB = nA + 2048;
    int ko = ((kt + 1) & (NK - 1)) * 8;   // wrapped tail = junk prefetch

    // ---- phase k0: quadrant (R0,C0)
    READ_AF(A, 0);
    READ_BF(B, bf0, 0);
    gl16(pA[0] + ko, nA + 0 * 512 + w * 64);
    gl16(pA[1] + ko, nA + 1 * 512 + w * 64);
    MEMFENCE;
    asm volatile("s_waitcnt lgkmcnt(8)" ::: "memory");
    __builtin_amdgcn_s_barrier();
    asm volatile("s_waitcnt lgkmcnt(0)" ::: "memory");
    __builtin_amdgcn_s_setprio(1);
    MFMA16(acc0, bf0);
    __builtin_amdgcn_s_setprio(0);
    asm volatile("s_waitcnt vmcnt(4)" ::: "memory");  // B1 of tile kt landed
    __builtin_amdgcn_s_barrier();
    MEMFENCE;

    // ---- phase k1: quadrant (R0,C1)
    READ_BF(B, bf1, 128);
    gl16(pB[0] + ko, nB + 0 * 512 + w * 64);
    gl16(pB[1] + ko, nB + 1 * 512 + w * 64);
    MEMFENCE;
    __builtin_amdgcn_s_barrier();
    asm volatile("s_waitcnt lgkmcnt(0)" ::: "memory");
    __builtin_amdgcn_s_setprio(1);
    MFMA16(acc1, bf1);
    __builtin_amdgcn_s_setprio(0);
    asm volatile("s_waitcnt vmcnt(4)" ::: "memory");  // A1 of tile kt landed
    __builtin_amdgcn_s_barrier();
    MEMFENCE;

    // ---- phase k2: quadrant (R1,C0)
    READ_AF(A, 128);
    gl16(pB[2] + ko, nB + 2 * 512 + w * 64);
    gl16(pB[3] + ko, nB + 3 * 512 + w * 64);
    MEMFENCE;
    __builtin_amdgcn_s_barrier();
    asm volatile("s_waitcnt lgkmcnt(0)" ::: "memory");
    __builtin_amdgcn_s_setprio(1);
    MFMA16(acc2, bf0);
    __builtin_amdgcn_s_setprio(0);
    __builtin_amdgcn_s_barrier();                     // no vmcnt needed here
    MEMFENCE;

    // ---- phase k3: quadrant (R1,C1)
    gl16(pA[2] + ko, nA + 2 * 512 + w * 64);
    gl16(pA[3] + ko, nA + 3 * 512 + w * 64);
    MEMFENCE;
    __builtin_amdgcn_s_barrier();
    __builtin_amdgcn_s_setprio(1);
    MFMA16(acc3, bf1);
    __builtin_amdgcn_s_setprio(0);
    asm volatile("s_waitcnt vmcnt(4)" ::: "memory");  // A0,B0 of kt+1 landed
    __builtin_amdgcn_s_barrier();
    MEMFENCE;
  }
  asm volatile("s_waitcnt vmcnt(0)" ::: "memory");    // settle DMA before exit

  // epilogue: silu(g)*u, pair (np, np+2) within each quadrant's acc
#pragma unroll
  for (int k = 0; k < 4; k++) {
    f32x4(*ak)[4] = (k == 0) ? acc0 : (k == 1) ? acc1 : (k == 2) ? acc2 : acc3;
    int Rk = (k >> 1) * 128, Ck = k & 1;
#pragma unroll
    for (int m2 = 0; m2 < 2; m2++)
#pragma unroll
      for (int np = 0; np < 2; np++)
#pragma unroll
        for (int q2 = 0; q2 < 4; q2++) {
          int row = Rk + wr * 32 + m2 * 16 + fs * 4 + q2;
          int col = n0 + (Ck * 2 + wc) * 32 + np * 16 + fr;
          float g = ak[m2][np][q2], u = ak[m2][np + 2][q2];
          float h = g * u / (1.f + expf(-g));
          __bf16 hb = (__bf16)h;
          int grow = m0 + row;
          if (sh) hs[(size_t)grow * I_DIM + col] = hb;
          else if (grow < count) hr[(size_t)(base + grow) * I_DIM + col] = hb;
        }
  }
}

// Down GEMM. Block 256 x 256, same quadrant-phase schedule.
__global__ __launch_bounds__(512, 2) void k_down8(
    const __bf16* __restrict__ hs, const __bf16* __restrict__ hr,
    const __bf16* __restrict__ wdb, const __bf16* __restrict__ sdb,
    const int* __restrict__ counts,
    float* __restrict__ out, float* __restrict__ y) {
  int z = blockIdx.z;
  int m0 = blockIdx.y * 256, n0 = blockIdx.x * 256;
  bool sh = (z == NE);
  int count, base = 0;
  const __bf16 *B, *A;
  if (sh) {
    count = NT; B = sdb; A = hs;
  } else {
    count = counts[z];
    if (m0 >= count) return;
    for (int e = 0; e < z; e++) base += counts[e];
    B = wdb + (size_t)z * (H_DIM * I_DIM);
    A = hr + (size_t)base * I_DIM;
  }

  __shared__ bf16x8 lds[8192];

  int tid = threadIdx.x, lane = tid & 63, w = tid >> 6;
  int wr = w >> 1, wc = w & 1;
  int fr = lane & 15, fs = lane >> 4;

  const bf16x8* a8 = (const bf16x8*)A;
  const bf16x8* b8 = (const bf16x8*)B;

  const bf16x8* pA[4];
  const bf16x8* pB[4];
#pragma unroll
  for (int q = 0; q < 4; q++) {
    int c = q * 512 + tid;
    int r = c >> 3, j = (c & 7) ^ (r & 7);
    int ra = m0 + r; if (ra >= count) ra = count - 1;
    pA[q] = a8 + (size_t)ra * (I_DIM / 8) + j;
    pB[q] = b8 + (size_t)(n0 + r) * (I_DIM / 8) + j;
  }

  f32x4 acc0[2][4], acc1[2][4], acc2[2][4], acc3[2][4];
#pragma unroll
  for (int m2 = 0; m2 < 2; m2++)
#pragma unroll
    for (int n = 0; n < 4; n++) {
      acc0[m2][n] = (f32x4){0.f, 0.f, 0.f, 0.f};
      acc1[m2][n] = (f32x4){0.f, 0.f, 0.f, 0.f};
      acc2[m2][n] = (f32x4){0.f, 0.f, 0.f, 0.f};
      acc3[m2][n] = (f32x4){0.f, 0.f, 0.f, 0.f};
    }

  {
    bf16x8* dA = lds;
    bf16x8* dB = lds + 2048;
    gl16(pA[0], dA + 0 * 512 + w * 64); gl16(pA[1], dA + 1 * 512 + w * 64);
    gl16(pB[0], dB + 0 * 512 + w * 64); gl16(pB[1], dB + 1 * 512 + w * 64);
    gl16(pB[2], dB + 2 * 512 + w * 64); gl16(pB[3], dB + 3 * 512 + w * 64);
    gl16(pA[2], dA + 2 * 512 + w * 64); gl16(pA[3], dA + 3 * 512 + w * 64);
  }
  asm volatile("s_waitcnt vmcnt(4)" ::: "memory");
  __builtin_amdgcn_s_barrier();
  MEMFENCE;

  const int NK = I_DIM / 64;  // 32
  bf16x8 af[2][2], bf0[4][2], bf1[4][2];
  for (int kt = 0; kt < NK; ++kt) {
    const bf16x8* Ab = lds + (kt & 1) * 4096;
    const bf16x8* Bb = Ab + 2048;
    bf16x8* nA = lds + (((kt & 1) ^ 1)) * 4096;
    bf16x8* nB = nA + 2048;
    int ko = ((kt + 1) & (NK - 1)) * 8;

    READ_AF(Ab, 0);
    READ_BF(Bb, bf0, 0);
    gl16(pA[0] + ko, nA + 0 * 512 + w * 64);
    gl16(pA[1] + ko, nA + 1 * 512 + w * 64);
    MEMFENCE;
    asm volatile("s_waitcnt lgkmcnt(8)" ::: "memory");
    __builtin_amdgcn_s_barrier();
    asm volatile("s_waitcnt lgkmcnt(0)" ::: "memory");
    __builtin_amdgcn_s_setprio(1);
    MFMA16(acc0, bf0);
    __builtin_amdgcn_s_setprio(0);
    asm volatile("s_waitcnt vmcnt(4)" ::: "memory");
    __builtin_amdgcn_s_barrier();
    MEMFENCE;

    READ_BF(Bb, bf1, 128);
    gl16(pB[0] + ko, nB + 0 * 512 + w * 64);
    gl16(pB[1] + ko, nB + 1 * 512 + w * 64);
    MEMFENCE;
    __builtin_amdgcn_s_barrier();
    asm volatile("s_waitcnt lgkmcnt(0)" ::: "memory");
    __builtin_amdgcn_s_setprio(1);
    MFMA16(acc1, bf1);
    __builtin_amdgcn_s_setprio(0);
    asm volatile("s_waitcnt vmcnt(4)" ::: "memory");
    __builtin_amdgcn_s_barrier();
    MEMFENCE;

    READ_AF(Ab, 128);
    gl16(pB[2] + ko, nB + 2 * 512 + w * 64);
    gl16(pB[3] + ko, nB + 3 * 512 + w * 64);
    MEMFENCE;
    __builtin_amdgcn_s_barrier();
    asm volatile("s_waitcnt lgkmcnt(0)" ::: "memory");
    __builtin_amdgcn_s_setprio(1);
    MFMA16(acc2, bf0);
    __builtin_amdgcn_s_setprio(0);
    __builtin_amdgcn_s_barrier();
    MEMFENCE;

    gl16(pA[2] + ko, nA + 2 * 512 + w * 64);
    gl16(pA[3] + ko, nA + 3 * 512 + w * 64);
    MEMFENCE;
    __builtin_amdgcn_s_barrier();
    __builtin_amdgcn_s_setprio(1);
    MFMA16(acc3, bf1);
    __builtin_amdgcn_s_setprio(0);
    asm volatile("s_waitcnt vmcnt(4)" ::: "memory");
    __builtin_amdgcn_s_barrier();
    MEMFENCE;
  }
  asm volatile("s_waitcnt vmcnt(0)" ::: "memory");

#pragma unroll
  for (int k = 0; k < 4; k++) {
    f32x4(*ak)[4] = (k == 0) ? acc0 : (k == 1) ? acc1 : (k == 2) ? acc2 : acc3;
    int Rk = (k >> 1) * 128, Ck = (k & 1) * 128;
#pragma unroll
    for (int m2 = 0; m2 < 2; m2++)
#pragma unroll
      for (int n = 0; n < 4; n++)
#pragma unroll
        for (int q2 = 0; q2 < 4; q2++) {
          int row = Rk + wr * 32 + m2 * 16 + fs * 4 + q2;
          int col = n0 + Ck + wc * 64 + n * 16 + fr;
          float v = ak[m2][n][q2];
          int grow = m0 + row;
          if (sh) out[(size_t)grow * H_DIM + col] = v;
          else if (grow < count) y[(size_t)(base + grow) * H_DIM + col] = v;
        }
  }
}

__global__ __launch_bounds__(256) void k_combine(
    const float* __restrict__ y, const int* __restrict__ counts,
    const int* __restrict__ tE, const int* __restrict__ tP,
    const float* __restrict__ tG, float* __restrict__ out) {
  int t = blockIdx.x;
  int c = threadIdx.x;  // H/4 = 256 float4 per token row
  int bases[NE];
  int s = 0;
#pragma unroll
  for (int e = 0; e < NE; e++) { bases[e] = s; s += counts[e]; }
  int e0 = tE[t * 2], e1 = tE[t * 2 + 1];
  int r0 = bases[e0] + tP[t * 2], r1 = bases[e1] + tP[t * 2 + 1];
  float g0 = tG[t * 2], g1 = tG[t * 2 + 1];
  const float4* y4 = (const float4*)y;
  float4* o4 = (float4*)out;
  float4 sv = o4[(size_t)t * (H_DIM / 4) + c];
  float4 a = y4[(size_t)r0 * (H_DIM / 4) + c];
  float4 b = y4[(size_t)r1 * (H_DIM / 4) + c];
  sv.x += g0 * a.x + g1 * b.x;
  sv.y += g0 * a.y + g1 * b.y;
  sv.z += g0 * a.z + g1 * b.z;
  sv.w += g0 * a.w + g1 * b.w;
  o4[(size_t)t * (H_DIM / 4) + c] = sv;
}

extern "C" void kernel_launch(void* const* d_in, const int* in_sizes, int n_in,
                              void* d_out, int out_size, void* d_ws, size_t ws_size,
                              hipStream_t stream) {
  const float* x = (const float*)d_in[0];
  const float* sg_w = (const float*)d_in[1];
  const float* su_w = (const float*)d_in[2];
  const float* sd_w = (const float*)d_in[3];
  const float* router_w = (const float*)d_in[4];
  const float* routing_bias = (const float*)d_in[5];
  const float* wg = (const float*)d_in[6];
  const float* wu = (const float*)d_in[7];
  const float* wd = (const float*)d_in[8];
  float* out = (float*)d_out;
  char* ws = (char*)d_ws;

  __bf16* xb  = (__bf16*)(ws + 0);            //  8,388,608
  __bf16* hs  = (__bf16*)(ws + 8388608);      // 16,777,216
  __bf16* hr  = (__bf16*)(ws + 25165824);     // 33,554,432
  float*  y   = (float*)(ws + 58720256);      // 33,554,432
  __bf16* wgb = (__bf16*)(ws + 92274688);     // 33,554,432
  __bf16* wub = (__bf16*)(ws + 125829120);    // 33,554,432
  __bf16* wdb = (__bf16*)(ws + 159383552);    // 33,554,432
  __bf16* sgb = (__bf16*)(ws + 192937984);    //  4,194,304
  __bf16* sub = (__bf16*)(ws + 197132288);    //  4,194,304
  __bf16* sdb = (__bf16*)(ws + 201326592);    //  4,194,304
  int* counts = (int*)(ws + 205520896);
  int* list   = (int*)(ws + 205520960);       // 131,072
  int* tE     = (int*)(ws + 205652032);       // 32,768
  int* tP     = (int*)(ws + 205684800);       // 32,768
  float* tG   = (float*)(ws + 205717568);     // 32,768

  hipMemsetAsync(counts, 0, NE * sizeof(int), stream);
  k_castall<<<27648, 256, 0, stream>>>(wg, wu, wd, sg_w, su_w, sd_w,
                                       wgb, wub, wdb, sgb, sub, sdb);
  k_router<<<NT / 4, 256, 0, stream>>>(x, router_w, routing_bias, xb,
                                       counts, list, tE, tP, tG);
  dim3 gu(I_DIM / 128, NT / 256, NE + 1);
  k_upgate8<<<gu, 512, 0, stream>>>(xb, wgb, wub, sgb, sub, counts, list, hs, hr);
  dim3 gd(H_DIM / 256, NT / 256, NE + 1);
  k_down8<<<gd, 512, 0, stream>>>(hs, hr, wdb, sdb, counts, out, y);
  k_combine<<<NT, 256, 0, stream>>>(y, counts, tE, tP, tG, out);
}